// Round 11
// baseline (2799.126 us; speedup 1.0000x reference)
//
#include <hip/hip_runtime.h>
#include <stdint.h>

typedef _Float16 v8hf __attribute__((ext_vector_type(8)));
typedef float v4f __attribute__((ext_vector_type(4)));
typedef unsigned long long u64t;

static __device__ __forceinline__ uint16_t f2h(float f){ _Float16 h=(_Float16)f; uint16_t u; __builtin_memcpy(&u,&h,2); return u; }
static __device__ __forceinline__ float h2f(uint16_t u){ _Float16 h; __builtin_memcpy(&h,&u,2); return (float)h; }
static __device__ __forceinline__ float fsig(float x){ return __builtin_amdgcn_rcpf(1.f + __expf(-x)); }
static __device__ __forceinline__ float ftanh(float x){ return 2.f*__builtin_amdgcn_rcpf(1.f + __expf(-2.f*x)) - 1.f; }

#define P0AOFF 65536
#define P1OFF  98304
#define MSOFF  114688
#define B1OFF  114944
#define CT0OFF 115200
#define CT1OFF 115204
#define LDSSZ  115264

// In-register 4x4 transpose across lane-quads (R10-proven).
__device__ __forceinline__ v4f quad_transpose(v4f v, int p) {
#pragma unroll
    for (int a = 1; a < 4; ++a) {
        v4f t;
#pragma unroll
        for (int j = 0; j < 4; ++j) t[j] = __shfl_xor(v[j ^ a], a);
#pragma unroll
        for (int j = 0; j < 4; ++j) if ((p ^ j) == a) v[j] = t[j];
    }
    return v;
}

// lens[b] = sum(mask[b,:]); gmax[group] = max len. Detects bool vs int32 mask layout.
__global__ __launch_bounds__(64) void setup_lens(const void* mask, int* lens, int* gmax) {
    int b = blockIdx.x;
    int lane = threadIdx.x;
    const unsigned char* mp = (const unsigned char*)mask;
    int isbyte = (mp[1] != 0);
    int cnt = 0;
    if (isbyte) {
        const unsigned char* row = mp + (size_t)b * 512;
        for (int i = lane; i < 512; i += 64) cnt += (row[i] != 0) ? 1 : 0;
    } else {
        const int* row = ((const int*)mask) + (size_t)b * 512;
        for (int i = lane; i < 512; i += 64) cnt += (row[i] != 0) ? 1 : 0;
    }
#pragma unroll
    for (int off = 32; off > 0; off >>= 1) cnt += __shfl_down(cnt, off);
    if (lane == 0) { lens[b] = cnt; atomicMax(&gmax[b >> 4], cnt); }
}

// All-wave poll of 32 flag slots (R7-proven pattern, duplicated per wave so no barrier).
__device__ __forceinline__ void poll32(const unsigned* slotbase, unsigned tgt, int lane) {
    const unsigned* sp = slotbase + ((lane & 31) << 4);
    long guard = 0;
    for (;;) {
        unsigned v = (lane < 32)
            ? __hip_atomic_load(sp, __ATOMIC_RELAXED, __HIP_MEMORY_SCOPE_AGENT)
            : 0xFFFFFFFFu;
        if (__ballot(v >= tgt) == ~0ull) break;
        __builtin_amdgcn_s_sleep(1);
        if (++guard > 150000L) break;   // loud failure, no hang
    }
}

// Wave-drain + monotone LDS-counter aggregation; 4th wave issues the global release.
__device__ __forceinline__ void agg_release(char* sm, int ctroff, unsigned epoch_t,
                                            unsigned* gslot, int lane) {
    asm volatile("s_waitcnt vmcnt(0)" ::: "memory");   // this wave's publishes ACKed
    if (lane == 0) {
        unsigned old = atomicAdd((unsigned*)(sm + ctroff), 1u);
        if (old == 4u * epoch_t + 3u)
            __hip_atomic_fetch_add(gslot, 1u, __ATOMIC_RELAXED, __HIP_MEMORY_SCOPE_AGENT);
    }
}

// Merged persistent kernel: layer-0 step t and layer-1 step t-1 per iteration.
// Split-flag early-release schedule: flag0 released after gates0 (~1us mark),
// consumed at epoch end; flag1 released after gates1 (~2.3us), consumed next
// epoch mid — each IC round trip overlaps the other layer's compute.
__global__ __launch_bounds__(256, 1) void lstm_merged(
    const float* __restrict__ x, const float* __restrict__ Wk0, const float* __restrict__ Wr0,
    const float* __restrict__ b0, const float* __restrict__ Wk1, const float* __restrict__ Wr1,
    const float* __restrict__ b1, const float* __restrict__ gamma, const float* __restrict__ beta,
    const int* __restrict__ lens, const int* __restrict__ gmax,
    unsigned* __restrict__ slots, uint16_t* __restrict__ h0buf, uint16_t* __restrict__ h1hist)
{
    extern __shared__ char sm[];
    const int tid = threadIdx.x;
    const int lane = tid & 63;
    const int wv = tid >> 6;
    const int g  = blockIdx.x & 7;
    const int cs = blockIdx.x >> 3;
    const int u0 = cs << 4;

    const int rr = lane & 15;
    const int kb = (lane >> 4) << 3;

    // ---- weights: Wr0 -> LDS (R10 column order); Wr1/(gamma.*Wk1) -> VGPR frags ----
    for (int idx = tid; idx < 512 * 64; idx += 256) {
        int k = idx >> 6, j = idx & 63;
        size_t col = ((size_t)(j & 3) << 9) + u0 + ((j >> 4) << 2) + ((j >> 2) & 3);
        float v = Wr0[(size_t)k * 2048 + col];
        int byte = ((j << 10) + (k << 1)) ^ ((j & 7) << 4);
        *(uint16_t*)(sm + byte) = f2h(v);
    }
    for (int i = tid; i < 12288; i += 256) ((uint32_t*)(sm + P0AOFF))[i] = 0u;  // P0A,P0B,P1
    if (tid < 16) {   // init both stats sets: mu=0, rs=rsqrt(1e-3)
        ((float*)(sm + MSOFF))[tid] = 0.f;       ((float*)(sm + MSOFF))[16 + tid] = rsqrtf(1e-3f);
        ((float*)(sm + MSOFF + 128))[tid] = 0.f; ((float*)(sm + MSOFF + 128))[16 + tid] = rsqrtf(1e-3f);
    }
    if (tid == 0) { *(unsigned*)(sm + CT0OFF) = 0u; *(unsigned*)(sm + CT1OFF) = 0u; }

    v8hf wR[16], wK[16];
    {
        const size_t col = ((size_t)(rr & 3) << 9) + u0 + (wv << 2) + ((rr >> 2) & 3);
        float sb = 0.f;
#pragma unroll
        for (int kk = 0; kk < 16; ++kk) {
#pragma unroll
            for (int j = 0; j < 8; ++j) {
                int k = (kk << 5) + kb + j;
                float wr = Wr1[(size_t)k * 2048 + col];
                float wk = Wk1[(size_t)k * 2048 + col];
                wR[kk][j] = (_Float16)wr;
                wK[kk][j] = (_Float16)(gamma[k] * wk);
                sb += beta[k] * wk;
            }
        }
        sb += __shfl_xor(sb, 16); sb += __shfl_xor(sb, 32);
        if (lane < 16)
            ((float*)(sm + B1OFF))[(wv << 4) + lane] = b1[col] + sb;
    }

    // per-lane gate constants: lane -> (row, unit) after quad transpose (R10)
    const int row = ((lane >> 4) << 2) + (lane & 3);
    const int ul  = (lane >> 2) & 3;
    const int myu = u0 + (wv << 2) + ul;
    float wk0r[12], b0r[4], b1r[4];
#pragma unroll
    for (int G = 0; G < 4; ++G) {
#pragma unroll
        for (int f = 0; f < 3; ++f) wk0r[f * 4 + G] = Wk0[(size_t)f * 2048 + (G << 9) + myu];
        b0r[G] = b0[(G << 9) + myu];
    }
    __syncthreads();
#pragma unroll
    for (int G = 0; G < 4; ++G)
        b1r[G] = ((const float*)(sm + B1OFF))[(wv << 4) + (ul << 2) + G];

    const int len_row = lens[(g << 4) + row];
    const int ml = gmax[g];
    unsigned* slot0g = slots + (g << 10);          // flag0: 32 slots x 64B
    unsigned* slot1g = slot0g + 512;               // flag1: 32 slots x 64B
    uint16_t* hh = h1hist + (size_t)g * 4194304;
    float c0 = 0.f, c1 = 0.f, ph0 = 0.f, ph1 = 0.f;
    const int lp = lane & 3;
    float px0, px1, px2;
    { const float* xp = x + ((size_t)((g << 4) + row) * 512) * 3;
      px0 = xp[0]; px1 = xp[1]; px2 = xp[2]; }
    __syncthreads();

    for (int t = 0;; ++t) {
        const int par = t & 1;
        const char* p0base = sm + P0AOFF + (par << 14);
        const float* muSp = (const float*)(sm + MSOFF + (par << 7));

        // ---- PHASE 1: chains 0 & K (both read P0 only) ----
        const float mu_r = muSp[rr], rs_r = muSp[16 + rr];
        const _Float16 rsh = (_Float16)rs_r;
        const _Float16 mrsh = (_Float16)(-mu_r * rs_r);
        v8hf rs8, mrs8;
#pragma unroll
        for (int j = 0; j < 8; ++j) { rs8[j] = rsh; mrs8[j] = mrsh; }
        v4f acc0 = {0,0,0,0}, accK = {0,0,0,0};
#pragma unroll
        for (int kk = 0; kk < 16; ++kk) {
            int k = kb + (kk << 5);
            int ab = ((rr << 10) + (k << 1)) ^ ((rr & 7) << 4);
            v8hf a0 = *(const v8hf*)(p0base + ab);
            int jr = (wv << 4) + rr;
            int bb = ((jr << 10) + (k << 1)) ^ ((jr & 7) << 4);
            v8hf bf = *(const v8hf*)(sm + bb);
            acc0 = __builtin_amdgcn_mfma_f32_16x16x32_f16(a0, bf, acc0, 0, 0, 0);
            v8hf an = a0 * rs8 + mrs8;
            accK = __builtin_amdgcn_mfma_f32_16x16x32_f16(an, wK[kk], accK, 0, 0, 0);
        }

        // ---- PHASE 2: gates0, publish h0[t], EARLY release flag0 ----
        if (t < ml) {
            v4f z0 = quad_transpose(acc0, lp);
            float zg[4];
#pragma unroll
            for (int G = 0; G < 4; ++G)
                zg[G] = z0[G] + px0 * wk0r[G] + px1 * wk0r[4 + G] + px2 * wk0r[8 + G] + b0r[G];
            float si = fsig(zg[0]), sf = fsig(zg[1]);
            float tg = ftanh(zg[2]), so = fsig(zg[3]);
            float cn = sf * c0 + si * tg;
            float hn = so * ftanh(cn);
            if (t < len_row) c0 = cn; else hn = ph0;
            ph0 = hn;
            unsigned hu = f2h(hn);
            unsigned x4 = __shfl_xor(hu, 4);
            unsigned lo = ((lane & 4) == 0) ? (hu | (x4 << 16)) : (x4 | (hu << 16));
            unsigned hi = __shfl_xor(lo, 8);
            u64t v = ((lane & 8) == 0) ? ((u64t)lo | ((u64t)hi << 32)) : ((u64t)hi | ((u64t)lo << 32));
            size_t sb = (size_t)((((t + 1) & 1) << 3) + g) * 8192;
            if ((lane & 12) == 0)
                __hip_atomic_store((u64t*)(h0buf + sb + (row << 9) + u0 + (wv << 2)), v,
                                   __ATOMIC_RELAXED, __HIP_MEMORY_SCOPE_AGENT);
            agg_release(sm, CT0OFF, (unsigned)t, slot0g + (cs << 4), lane);
        }

        // ---- PHASE 3: wait flag1 >= t (released last epoch), stage P1 <- h1[t-2] ----
        if (t >= 2) {
            poll32(slot1g, (unsigned)t, lane);
            const u64t* src = (const u64t*)(hh + (size_t)(t - 2) * 8192);
            u64t w[8];
#pragma unroll
            for (int i = 0; i < 4; ++i) {
                int c = 2 * (i * 256 + tid);
                w[2*i]   = __hip_atomic_load(src + c,     __ATOMIC_RELAXED, __HIP_MEMORY_SCOPE_AGENT);
                w[2*i+1] = __hip_atomic_load(src + c + 1, __ATOMIC_RELAXED, __HIP_MEMORY_SCOPE_AGENT);
            }
#pragma unroll
            for (int i = 0; i < 4; ++i) {
                int byte = (i * 256 + tid) << 4;
                int r2 = byte >> 10;
                int sbz = byte ^ ((r2 & 7) << 4);
                uint4 u;
                u.x = (unsigned)w[2*i];   u.y = (unsigned)(w[2*i]   >> 32);
                u.z = (unsigned)w[2*i+1]; u.w = (unsigned)(w[2*i+1] >> 32);
                *(uint4*)(sm + P1OFF + sbz) = u;
            }
        }
        __syncthreads();                           // P1 ready for chainR

        // ---- PHASE 4: chainR, gates1, publish h1[t-1], release flag1 ----
        v4f accR = {0,0,0,0};
#pragma unroll
        for (int kk = 0; kk < 16; ++kk) {
            int k = kb + (kk << 5);
            int ab = ((rr << 10) + (k << 1)) ^ ((rr & 7) << 4);
            v8hf a1 = *(const v8hf*)(sm + P1OFF + ab);
            accR = __builtin_amdgcn_mfma_f32_16x16x32_f16(a1, wR[kk], accR, 0, 0, 0);
        }
        if (t >= 1) {
            v4f z1 = quad_transpose(accK + accR, lp);
            float zg[4];
#pragma unroll
            for (int G = 0; G < 4; ++G) zg[G] = z1[G] + b1r[G];
            float si = fsig(zg[0]), sf = fsig(zg[1]);
            float tg = ftanh(zg[2]), so = fsig(zg[3]);
            float cn = sf * c1 + si * tg;
            float hn = so * ftanh(cn);
            if (t - 1 < len_row) c1 = cn; else hn = ph1;
            ph1 = hn;
            unsigned hu = f2h(hn);
            unsigned x4 = __shfl_xor(hu, 4);
            unsigned lo = ((lane & 4) == 0) ? (hu | (x4 << 16)) : (x4 | (hu << 16));
            unsigned hi = __shfl_xor(lo, 8);
            u64t v = ((lane & 8) == 0) ? ((u64t)lo | ((u64t)hi << 32)) : ((u64t)hi | ((u64t)lo << 32));
            if ((lane & 12) == 0)
                *(u64t*)(hh + (size_t)(t - 1) * 8192 + (row << 9) + u0 + (wv << 2)) = v;
        }
        if (t == ml) break;                        // last h1 published; done
        agg_release(sm, CT1OFF, (unsigned)t, slot1g + (cs << 4), lane);

        // off critical path: prefetch x[t+1]
        { int tn = (t + 1 < ml) ? t + 1 : ml - 1;
          const float* xp = x + ((size_t)((g << 4) + row) * 512 + tn) * 3;
          px0 = xp[0]; px1 = xp[1]; px2 = xp[2]; }

        // ---- PHASE 5: wait flag0 >= t+1 (released this epoch ~2us ago), stage P0 + stats ----
        poll32(slot0g, (unsigned)(t + 1), lane);
        {
            const u64t* src = (const u64t*)(h0buf + (size_t)((((t + 1) & 1) << 3) + g) * 8192);
            float* muN = (float*)(sm + MSOFF + ((par ^ 1) << 7));
            char* p0n = sm + P0AOFF + ((par ^ 1) << 14);
            u64t w[8];
#pragma unroll
            for (int i = 0; i < 4; ++i) {
                int c = 2 * (i * 256 + tid);
                w[2*i]   = __hip_atomic_load(src + c,     __ATOMIC_RELAXED, __HIP_MEMORY_SCOPE_AGENT);
                w[2*i+1] = __hip_atomic_load(src + c + 1, __ATOMIC_RELAXED, __HIP_MEMORY_SCOPE_AGENT);
            }
#pragma unroll
            for (int i = 0; i < 4; ++i) {
                float ps = 0.f, pq = 0.f;
#pragma unroll
                for (int k = 0; k < 2; ++k) {
                    u64t ww = w[2*i + k];
#pragma unroll
                    for (int h = 0; h < 4; ++h) {
                        float f = h2f((uint16_t)(ww >> (16*h)));
                        ps += f; pq += f * f;
                    }
                }
#pragma unroll
                for (int m = 1; m < 64; m <<= 1) { ps += __shfl_xor(ps, m); pq += __shfl_xor(pq, m); }
                int byte = (i * 256 + tid) << 4;
                int r2 = byte >> 10;
                if (lane == 0) {
                    float mu = ps * (1.f / 512.f);
                    muN[r2] = mu;
                    muN[16 + r2] = rsqrtf(pq * (1.f / 512.f) - mu * mu + 1e-3f);
                }
                int sbz = byte ^ ((r2 & 7) << 4);
                uint4 u;
                u.x = (unsigned)w[2*i];   u.y = (unsigned)(w[2*i]   >> 32);
                u.z = (unsigned)w[2*i+1]; u.w = (unsigned)(w[2*i+1] >> 32);
                *(uint4*)(p0n + sbz) = u;
            }
        }
        __syncthreads();                           // P0', stats visible; next epoch
    }
}

// Trailing kernel: out[b,t] = softmax(LN(h1[min(t,ml-1)]) @ Wfc + bfc). One wave per (b,t).
__global__ __launch_bounds__(256) void finalize(
    const uint16_t* __restrict__ h1hist, const int* __restrict__ gmax,
    const float* __restrict__ gamma, const float* __restrict__ beta,
    const float* __restrict__ Wfc, const float* __restrict__ bfc,
    float* __restrict__ out)
{
    int wv = threadIdx.x >> 6, lane = threadIdx.x & 63;
    int rid = blockIdx.x * 4 + wv;
    int b = rid >> 9, t = rid & 511;
    int g = b >> 4, r = b & 15;
    int ml = gmax[g];
    int ts = t < ml ? t : ml - 1;
    const uint16_t* hp = h1hist + (size_t)g * 4194304 + (size_t)ts * 8192 + (r << 9) + (lane << 3);
    v8hf h8 = *(const v8hf*)hp;
    float hv[8]; float s = 0.f, q2 = 0.f;
#pragma unroll
    for (int j = 0; j < 8; ++j) { float f = (float)h8[j]; hv[j] = f; s += f; q2 += f * f; }
#pragma unroll
    for (int m = 1; m < 64; m <<= 1) { s += __shfl_xor(s, m); q2 += __shfl_xor(q2, m); }
    float mu = s * (1.f / 512.f);
    float rstd = rsqrtf(q2 * (1.f / 512.f) - mu * mu + 1e-3f);
    float p0=0,p1=0,p2=0,p3=0,p4=0;
#pragma unroll
    for (int j = 0; j < 8; ++j) {
        int k = (lane << 3) + j;
        float hn = (hv[j] - mu) * rstd * gamma[k] + beta[k];
        const float* wf = Wfc + (size_t)k * 5;
        p0 += hn*wf[0]; p1 += hn*wf[1]; p2 += hn*wf[2]; p3 += hn*wf[3]; p4 += hn*wf[4];
    }
#pragma unroll
    for (int m = 1; m < 64; m <<= 1) {
        p0 += __shfl_xor(p0,m); p1 += __shfl_xor(p1,m); p2 += __shfl_xor(p2,m);
        p3 += __shfl_xor(p3,m); p4 += __shfl_xor(p4,m);
    }
    if (lane == 0) {
        float l0=p0+bfc[0], l1=p1+bfc[1], l2=p2+bfc[2], l3=p3+bfc[3], l4=p4+bfc[4];
        float mx = fmaxf(fmaxf(fmaxf(l0,l1),fmaxf(l2,l3)),l4);
        float e0=__expf(l0-mx), e1=__expf(l1-mx), e2=__expf(l2-mx), e3=__expf(l3-mx), e4=__expf(l4-mx);
        float inv = 1.f/(e0+e1+e2+e3+e4);
        float* op = out + (size_t)rid * 5;
        op[0]=e0*inv; op[1]=e1*inv; op[2]=e2*inv; op[3]=e3*inv; op[4]=e4*inv;
    }
}

extern "C" void kernel_launch(void* const* d_in, const int* in_sizes, int n_in,
                              void* d_out, int out_size, void* d_ws, size_t ws_size,
                              hipStream_t stream) {
    (void)in_sizes; (void)n_in; (void)out_size;
    const float* x     = (const float*)d_in[0];
    const void*  mask  = d_in[1];
    const float* Wk0   = (const float*)d_in[2];
    const float* Wr0   = (const float*)d_in[3];
    const float* b0    = (const float*)d_in[4];
    const float* Wk1   = (const float*)d_in[5];
    const float* Wr1   = (const float*)d_in[6];
    const float* b1    = (const float*)d_in[7];
    const float* gamma = (const float*)d_in[8];
    const float* beta  = (const float*)d_in[9];
    const float* Wfc   = (const float*)d_in[10];
    const float* bfc   = (const float*)d_in[11];
    float* out = (float*)d_out;
    char* ws = (char*)d_ws;
    unsigned* slots  = (unsigned*)(ws);            // 8 groups x 2 flags x 32 slots x 64B = 32KB
    int*      lens   = (int*)(ws + 32768);         // 128 ints
    int*      gmax   = (int*)(ws + 33280);         // 8 ints
    uint16_t* h0buf  = (uint16_t*)(ws + 36864);    // 2 x 8 x 16KB = 256KB
    uint16_t* h1hist = (uint16_t*)(ws + 299008);   // 8 x 512 x 16KB = 64MB
    if (ws_size < 67407872) return;

    hipFuncSetAttribute((const void*)lstm_merged, hipFuncAttributeMaxDynamicSharedMemorySize, LDSSZ);
    hipMemsetAsync(ws, 0, 36864, stream);   // slots/lens/gmax zeroed every call
    setup_lens<<<128, 64, 0, stream>>>(mask, lens, gmax);
    lstm_merged<<<256, 256, LDSSZ, stream>>>(x, Wk0, Wr0, b0, Wk1, Wr1, b1, gamma, beta,
                                             lens, gmax, slots, h0buf, h1hist);
    finalize<<<16384, 256, 0, stream>>>(h1hist, gmax, gamma, beta, Wfc, bfc, out);
}

// Round 12
// 2633.976 us; speedup vs baseline: 1.0627x; 1.0627x over previous
//
#include <hip/hip_runtime.h>
#include <stdint.h>

typedef _Float16 v8hf __attribute__((ext_vector_type(8)));
typedef float v4f __attribute__((ext_vector_type(4)));
typedef unsigned long long u64t;

static __device__ __forceinline__ uint16_t f2h(float f){ _Float16 h=(_Float16)f; uint16_t u; __builtin_memcpy(&u,&h,2); return u; }
static __device__ __forceinline__ float h2f(uint16_t u){ _Float16 h; __builtin_memcpy(&h,&u,2); return (float)h; }
static __device__ __forceinline__ float fsig(float x){ return __builtin_amdgcn_rcpf(1.f + __expf(-x)); }
static __device__ __forceinline__ float ftanh(float x){ return 2.f*__builtin_amdgcn_rcpf(1.f + __expf(-2.f*x)) - 1.f; }

#define P0OFF  65536
#define P1OFF  81920
#define MSOFF  98304
#define B1OFF  98560
#define LDSSZ  98944

// In-register 4x4 transpose across lane-quads (R10-proven).
__device__ __forceinline__ v4f quad_transpose(v4f v, int p) {
#pragma unroll
    for (int a = 1; a < 4; ++a) {
        v4f t;
#pragma unroll
        for (int j = 0; j < 4; ++j) t[j] = __shfl_xor(v[j ^ a], a);
#pragma unroll
        for (int j = 0; j < 4; ++j) if ((p ^ j) == a) v[j] = t[j];
    }
    return v;
}

// Fused stage of P0 (+ per-row LN stats) and P1 through the IC (R8/R10-proven).
__device__ __forceinline__ void stage_both(const uint16_t* __restrict__ s0,
                                           const uint16_t* __restrict__ s1,
                                           char* sm, float* muS, float* rsS, int doP1) {
    const int tid = threadIdx.x;
    const int lane = tid & 63;
    const u64t* a = (const u64t*)s0;
    const u64t* b = (const u64t*)s1;
    u64t va[8], vb[8];
#pragma unroll
    for (int i = 0; i < 4; ++i) {
        int c = 2 * (i * 256 + tid);
        va[2*i]   = __hip_atomic_load(a + c,     __ATOMIC_RELAXED, __HIP_MEMORY_SCOPE_AGENT);
        va[2*i+1] = __hip_atomic_load(a + c + 1, __ATOMIC_RELAXED, __HIP_MEMORY_SCOPE_AGENT);
    }
    if (doP1) {
#pragma unroll
        for (int i = 0; i < 4; ++i) {
            int c = 2 * (i * 256 + tid);
            vb[2*i]   = __hip_atomic_load(b + c,     __ATOMIC_RELAXED, __HIP_MEMORY_SCOPE_AGENT);
            vb[2*i+1] = __hip_atomic_load(b + c + 1, __ATOMIC_RELAXED, __HIP_MEMORY_SCOPE_AGENT);
        }
    }
#pragma unroll
    for (int i = 0; i < 4; ++i) {
        float ps = 0.f, pq = 0.f;
#pragma unroll
        for (int k = 0; k < 2; ++k) {
            u64t w = va[2*i + k];
#pragma unroll
            for (int h = 0; h < 4; ++h) {
                float f = h2f((uint16_t)(w >> (16*h)));
                ps += f; pq += f * f;
            }
        }
#pragma unroll
        for (int m = 1; m < 64; m <<= 1) { ps += __shfl_xor(ps, m); pq += __shfl_xor(pq, m); }
        int byte = (i * 256 + tid) << 4;
        int row = byte >> 10;
        if (lane == 0) {
            float mu = ps * (1.f / 512.f);
            muS[row] = mu;
            rsS[row] = rsqrtf(pq * (1.f / 512.f) - mu * mu + 1e-3f);
        }
        int sb = byte ^ ((row & 7) << 4);
        uint4 u;
        u.x = (unsigned)va[2*i];   u.y = (unsigned)(va[2*i]   >> 32);
        u.z = (unsigned)va[2*i+1]; u.w = (unsigned)(va[2*i+1] >> 32);
        *(uint4*)(sm + P0OFF + sb) = u;
        if (doP1) {
            uint4 v;
            v.x = (unsigned)vb[2*i];   v.y = (unsigned)(vb[2*i]   >> 32);
            v.z = (unsigned)vb[2*i+1]; v.w = (unsigned)(vb[2*i+1] >> 32);
            *(uint4*)(sm + P1OFF + sb) = v;
        }
    }
}

// lens[b] = sum(mask[b,:]); gmax[group] = max len. Detects bool vs int32 mask layout.
__global__ __launch_bounds__(64) void setup_lens(const void* mask, int* lens, int* gmax) {
    int b = blockIdx.x;
    int lane = threadIdx.x;
    const unsigned char* mp = (const unsigned char*)mask;
    int isbyte = (mp[1] != 0);
    int cnt = 0;
    if (isbyte) {
        const unsigned char* row = mp + (size_t)b * 512;
        for (int i = lane; i < 512; i += 64) cnt += (row[i] != 0) ? 1 : 0;
    } else {
        const int* row = ((const int*)mask) + (size_t)b * 512;
        for (int i = lane; i < 512; i += 64) cnt += (row[i] != 0) ? 1 : 0;
    }
#pragma unroll
    for (int off = 32; off > 0; off >>= 1) cnt += __shfl_down(cnt, off);
    if (lane == 0) { lens[b] = cnt; atomicMax(&gmax[b >> 4], cnt); }
}

// Merged persistent kernel: layer-0 step t and layer-1 step t-1 per iteration.
// K7-proven IC flag protocol; R10 quad-transpose register-gate structure.
// 3 barriers/epoch (R10's post-MFMA barrier removed: provably redundant —
// all stage-phase LDS writes are ordered after MFMA reads by barriers B & C).
__global__ __launch_bounds__(256, 1) void lstm_merged(
    const float* __restrict__ x, const float* __restrict__ Wk0, const float* __restrict__ Wr0,
    const float* __restrict__ b0, const float* __restrict__ Wk1, const float* __restrict__ Wr1,
    const float* __restrict__ b1, const float* __restrict__ gamma, const float* __restrict__ beta,
    const int* __restrict__ lens, const int* __restrict__ gmax,
    unsigned* __restrict__ slots, uint16_t* __restrict__ h0buf, uint16_t* __restrict__ h1hist)
{
    extern __shared__ char sm[];
    const int tid = threadIdx.x;
    const int lane = tid & 63;
    const int wv = tid >> 6;
    const int g  = blockIdx.x & 7;
    const int cs = blockIdx.x >> 3;
    const int u0 = cs << 4;

    const int rr = lane & 15;
    const int kb = (lane >> 4) << 3;

    // ---- weights: Wr0 -> LDS; Wr1/(gamma.*Wk1) -> VGPR frags. Column order:
    // LDS/frag row j (0..63): wave j>>4, unit u0 + ((j>>4)<<2) + ((j>>2)&3), gate j&3.
    for (int idx = tid; idx < 512 * 64; idx += 256) {
        int k = idx >> 6, j = idx & 63;
        size_t col = ((size_t)(j & 3) << 9) + u0 + ((j >> 4) << 2) + ((j >> 2) & 3);
        float v = Wr0[(size_t)k * 2048 + col];
        int byte = ((j << 10) + (k << 1)) ^ ((j & 7) << 4);
        *(uint16_t*)(sm + byte) = f2h(v);
    }
    for (int i = tid; i < 8192; i += 256) ((uint32_t*)(sm + P0OFF))[i] = 0u;  // zero P0,P1
    float* muS = (float*)(sm + MSOFF);
    float* rsS = muS + 16;
    if (tid < 16) { muS[tid] = 0.f; rsS[tid] = rsqrtf(1e-3f); }

    v8hf wR[16], wK[16];
    {
        const size_t col = ((size_t)(rr & 3) << 9) + u0 + (wv << 2) + ((rr >> 2) & 3);
        float sb = 0.f;
#pragma unroll
        for (int kk = 0; kk < 16; ++kk) {
#pragma unroll
            for (int j = 0; j < 8; ++j) {
                int k = (kk << 5) + kb + j;
                float wr = Wr1[(size_t)k * 2048 + col];
                float wk = Wk1[(size_t)k * 2048 + col];
                wR[kk][j] = (_Float16)wr;
                wK[kk][j] = (_Float16)(gamma[k] * wk);
                sb += beta[k] * wk;
            }
        }
        sb += __shfl_xor(sb, 16); sb += __shfl_xor(sb, 32);
        if (lane < 16)
            ((float*)(sm + B1OFF))[(wv << 4) + lane] = b1[col] + sb;
    }

    // ---- per-lane gate-phase constants: lane -> (row, unit) after transpose ----
    const int row = ((lane >> 4) << 2) + (lane & 3);
    const int ul  = (lane >> 2) & 3;
    const int myu = u0 + (wv << 2) + ul;
    float wk0r[12], b0r[4], b1r[4];
#pragma unroll
    for (int G = 0; G < 4; ++G) {
#pragma unroll
        for (int f = 0; f < 3; ++f) wk0r[f * 4 + G] = Wk0[(size_t)f * 2048 + (G << 9) + myu];
        b0r[G] = b0[(G << 9) + myu];
    }
    __syncthreads();
#pragma unroll
    for (int G = 0; G < 4; ++G)
        b1r[G] = ((const float*)(sm + B1OFF))[(wv << 4) + (ul << 2) + G];

    const int len_row = lens[(g << 4) + row];
    const int ml = gmax[g];
    unsigned* slotg = slots + (g << 9);            // 32 slots x 64B stride
    uint16_t* hh = h1hist + (size_t)g * 4194304;
    float c0 = 0.f, c1 = 0.f, ph0 = 0.f, ph1 = 0.f;
    const int lp = lane & 3;                       // quad position (row-in-quad post-transpose)
    float px0, px1, px2;
    { const float* xp = x + ((size_t)((g << 4) + row) * 512) * 3;
      px0 = xp[0]; px1 = xp[1]; px2 = xp[2]; }
    __syncthreads();

    for (int t = 0;; ++t) {
        // ---- MFMA phase: z0 = P0@Wr0, z1 = LNpk(P0)@(g.*Wk1) + P1@Wr1 ----
        const float mu_r = muS[rr], rs_r = rsS[rr];
        const _Float16 rsh = (_Float16)rs_r;
        const _Float16 mrsh = (_Float16)(-mu_r * rs_r);
        v8hf rs8, mrs8;
#pragma unroll
        for (int j = 0; j < 8; ++j) { rs8[j] = rsh; mrs8[j] = mrsh; }
        v4f acc0 = {0,0,0,0}, accK = {0,0,0,0}, accR = {0,0,0,0};
#pragma unroll
        for (int kk = 0; kk < 16; ++kk) {
            int k = kb + (kk << 5);
            int ab = ((rr << 10) + (k << 1)) ^ ((rr & 7) << 4);
            v8hf a0 = *(const v8hf*)(sm + P0OFF + ab);
            int jr = (wv << 4) + rr;
            int bb = ((jr << 10) + (k << 1)) ^ ((jr & 7) << 4);
            v8hf bf = *(const v8hf*)(sm + bb);
            acc0 = __builtin_amdgcn_mfma_f32_16x16x32_f16(a0, bf, acc0, 0, 0, 0);
            v8hf an = a0 * rs8 + mrs8;
            accK = __builtin_amdgcn_mfma_f32_16x16x32_f16(an, wK[kk], accK, 0, 0, 0);
            v8hf a1 = *(const v8hf*)(sm + P1OFF + ab);
            accR = __builtin_amdgcn_mfma_f32_16x16x32_f16(a1, wR[kk], accR, 0, 0, 0);
        }
        v4f z0 = quad_transpose(acc0, lp);          // lane -> 4 gates of (row, myu)
        v4f z1 = quad_transpose(accR + accK, lp);
        // (R10's barrier A removed here: gates are register-only; staging LDS
        //  writes are ordered after all MFMA LDS reads by barriers B & C.)

        // ---- gates (registers only) ----
        const u64t slotbase = (size_t)((((t + 1) & 1) << 3) + g) * 8192;
        if (t < ml) {   // layer-0 step t
            float zg[4];
#pragma unroll
            for (int G = 0; G < 4; ++G)
                zg[G] = z0[G] + px0 * wk0r[G] + px1 * wk0r[4 + G] + px2 * wk0r[8 + G] + b0r[G];
            float si = fsig(zg[0]), sf = fsig(zg[1]);
            float tg = ftanh(zg[2]), so = fsig(zg[3]);
            float cn = sf * c0 + si * tg;
            float hn = so * ftanh(cn);
            if (t < len_row) c0 = cn; else hn = ph0;
            ph0 = hn;
            unsigned hu = f2h(hn);
            unsigned x4 = __shfl_xor(hu, 4);
            unsigned lo = ((lane & 4) == 0) ? (hu | (x4 << 16)) : (x4 | (hu << 16));
            unsigned hi = __shfl_xor(lo, 8);
            u64t v = ((lane & 8) == 0) ? ((u64t)lo | ((u64t)hi << 32)) : ((u64t)hi | ((u64t)lo << 32));
            if ((lane & 12) == 0)
                __hip_atomic_store((u64t*)(h0buf + slotbase + (row << 9) + u0 + (wv << 2)), v,
                                   __ATOMIC_RELAXED, __HIP_MEMORY_SCOPE_AGENT);
        }
        if (t >= 1) {   // layer-1 step t-1
            float zg[4];
#pragma unroll
            for (int G = 0; G < 4; ++G) zg[G] = z1[G] + b1r[G];
            float si = fsig(zg[0]), sf = fsig(zg[1]);
            float tg = ftanh(zg[2]), so = fsig(zg[3]);
            float cn = sf * c1 + si * tg;
            float hn = so * ftanh(cn);
            if (t - 1 < len_row) c1 = cn; else hn = ph1;
            ph1 = hn;
            unsigned hu = f2h(hn);
            unsigned x4 = __shfl_xor(hu, 4);
            unsigned lo = ((lane & 4) == 0) ? (hu | (x4 << 16)) : (x4 | (hu << 16));
            unsigned hi = __shfl_xor(lo, 8);
            u64t v = ((lane & 8) == 0) ? ((u64t)lo | ((u64t)hi << 32)) : ((u64t)hi | ((u64t)lo << 32));
            if ((lane & 12) == 0)
                *(u64t*)(hh + (size_t)(t - 1) * 8192 + (row << 9) + u0 + (wv << 2)) = v;
        }
        if (t == ml) break;
        __syncthreads();                            // B: drains all waves' stores

        // ---- release (K7-proven): block leader bumps slot once ----
        if (tid == 0)
            __hip_atomic_fetch_add(slotg + (cs << 4), 1u,
                                   __ATOMIC_RELAXED, __HIP_MEMORY_SCOPE_AGENT);
        // off critical path: prefetch x[t+1]
        { int tn = (t + 1 < ml) ? t + 1 : ml - 1;
          const float* xp = x + ((size_t)((g << 4) + row) * 512 + tn) * 3;
          px0 = xp[0]; px1 = xp[1]; px2 = xp[2]; }
        // ---- wait (K7-proven): wave 0 polls 32 slots with s_sleep(1) ----
        if (tid < 32) {
            const unsigned tgt = (unsigned)(t + 1);
            const unsigned* sp = slotg + (tid << 4);
            long guard = 0;
            for (;;) {
                unsigned v = __hip_atomic_load(sp, __ATOMIC_RELAXED, __HIP_MEMORY_SCOPE_AGENT);
                if ((__ballot(v >= tgt) & 0xFFFFFFFFull) == 0xFFFFFFFFull) break;
                __builtin_amdgcn_s_sleep(1);
                if (++guard > 300000L) break;       // loud failure, no hang
            }
        }
        __syncthreads();                            // C
        // ---- stage next tiles: P0 <- h0[t] (+LN stats), P1 <- h1[t-1] ----
        stage_both(h0buf + (size_t)((((t + 1) & 1) << 3) + g) * 8192,
                   hh + (size_t)(t >= 1 ? t - 1 : 0) * 8192,
                   sm, muS, rsS, t >= 1);
        __syncthreads();                            // D
    }
}

// Trailing kernel: out[b,t] = softmax(LN(h1[min(t,ml-1)]) @ Wfc + bfc). One wave per (b,t).
__global__ __launch_bounds__(256) void finalize(
    const uint16_t* __restrict__ h1hist, const int* __restrict__ gmax,
    const float* __restrict__ gamma, const float* __restrict__ beta,
    const float* __restrict__ Wfc, const float* __restrict__ bfc,
    float* __restrict__ out)
{
    int wv = threadIdx.x >> 6, lane = threadIdx.x & 63;
    int rid = blockIdx.x * 4 + wv;
    int b = rid >> 9, t = rid & 511;
    int g = b >> 4, r = b & 15;
    int ml = gmax[g];
    int ts = t < ml ? t : ml - 1;
    const uint16_t* hp = h1hist + (size_t)g * 4194304 + (size_t)ts * 8192 + (r << 9) + (lane << 3);
    v8hf h8 = *(const v8hf*)hp;
    float hv[8]; float s = 0.f, q2 = 0.f;
#pragma unroll
    for (int j = 0; j < 8; ++j) { float f = (float)h8[j]; hv[j] = f; s += f; q2 += f * f; }
#pragma unroll
    for (int m = 1; m < 64; m <<= 1) { s += __shfl_xor(s, m); q2 += __shfl_xor(q2, m); }
    float mu = s * (1.f / 512.f);
    float rstd = rsqrtf(q2 * (1.f / 512.f) - mu * mu + 1e-3f);
    float p0=0,p1=0,p2=0,p3=0,p4=0;
#pragma unroll
    for (int j = 0; j < 8; ++j) {
        int k = (lane << 3) + j;
        float hn = (hv[j] - mu) * rstd * gamma[k] + beta[k];
        const float* wf = Wfc + (size_t)k * 5;
        p0 += hn*wf[0]; p1 += hn*wf[1]; p2 += hn*wf[2]; p3 += hn*wf[3]; p4 += hn*wf[4];
    }
#pragma unroll
    for (int m = 1; m < 64; m <<= 1) {
        p0 += __shfl_xor(p0,m); p1 += __shfl_xor(p1,m); p2 += __shfl_xor(p2,m);
        p3 += __shfl_xor(p3,m); p4 += __shfl_xor(p4,m);
    }
    if (lane == 0) {
        float l0=p0+bfc[0], l1=p1+bfc[1], l2=p2+bfc[2], l3=p3+bfc[3], l4=p4+bfc[4];
        float mx = fmaxf(fmaxf(fmaxf(l0,l1),fmaxf(l2,l3)),l4);
        float e0=__expf(l0-mx), e1=__expf(l1-mx), e2=__expf(l2-mx), e3=__expf(l3-mx), e4=__expf(l4-mx);
        float inv = 1.f/(e0+e1+e2+e3+e4);
        float* op = out + (size_t)rid * 5;
        op[0]=e0*inv; op[1]=e1*inv; op[2]=e2*inv; op[3]=e3*inv; op[4]=e4*inv;
    }
}

extern "C" void kernel_launch(void* const* d_in, const int* in_sizes, int n_in,
                              void* d_out, int out_size, void* d_ws, size_t ws_size,
                              hipStream_t stream) {
    (void)in_sizes; (void)n_in; (void)out_size;
    const float* x     = (const float*)d_in[0];
    const void*  mask  = d_in[1];
    const float* Wk0   = (const float*)d_in[2];
    const float* Wr0   = (const float*)d_in[3];
    const float* b0    = (const float*)d_in[4];
    const float* Wk1   = (const float*)d_in[5];
    const float* Wr1   = (const float*)d_in[6];
    const float* b1    = (const float*)d_in[7];
    const float* gamma = (const float*)d_in[8];
    const float* beta  = (const float*)d_in[9];
    const float* Wfc   = (const float*)d_in[10];
    const float* bfc   = (const float*)d_in[11];
    float* out = (float*)d_out;
    char* ws = (char*)d_ws;
    unsigned* slots  = (unsigned*)(ws);            // 8 groups x 32 slots x 64B = 16KB
    int*      lens   = (int*)(ws + 16384);         // 128 ints
    int*      gmax   = (int*)(ws + 16896);         // 8 ints
    uint16_t* h0buf  = (uint16_t*)(ws + 32768);    // 2 x 8 x 16KB = 256KB
    uint16_t* h1hist = (uint16_t*)(ws + 294912);   // 8 x 512 x 16KB = 64MB
    if (ws_size < 67403776) return;

    hipFuncSetAttribute((const void*)lstm_merged, hipFuncAttributeMaxDynamicSharedMemorySize, LDSSZ);
    hipMemsetAsync(ws, 0, 32768, stream);   // slots/lens/gmax zeroed every call
    setup_lens<<<128, 64, 0, stream>>>(mask, lens, gmax);
    lstm_merged<<<256, 256, LDSSZ, stream>>>(x, Wk0, Wr0, b0, Wk1, Wr1, b1, gamma, beta,
                                             lens, gmax, slots, h0buf, h1hist);
    finalize<<<16384, 256, 0, stream>>>(h1hist, gmax, gamma, beta, Wfc, bfc, out);
}